// Round 6
// baseline (1499.233 us; speedup 1.0000x reference)
//
#include <hip/hip_runtime.h>

typedef _Float16 f16;
typedef _Float16 f16x4 __attribute__((ext_vector_type(4)));
typedef _Float16 f16x8 __attribute__((ext_vector_type(8)));
typedef float f32x4 __attribute__((ext_vector_type(4)));

#define LRELU(v) ((v) >= 0.f ? (v) : 0.01f * (v))

__device__ __forceinline__ int swz(int a) { return a ^ (((a >> 7) & 7) << 4); }

#define BCAP 64

// ---------------- fused setup: feat_small + zero_cursor + weight prep ----------------
__global__ __launch_bounds__(256) void setup_kernel(
    const float* __restrict__ num_prop, const float* __restrict__ cat_prop,
    const float* __restrict__ W_num, const float* __restrict__ b_num,
    const float* __restrict__ W_cat, const float* __restrict__ b_cat,
    const float* __restrict__ W_des, const float* __restrict__ W_in,
    const float* __restrict__ W_root, const float* __restrict__ W_rel,
    const float* __restrict__ W_o1,
    f16* __restrict__ x0, int* __restrict__ cursor,
    f16* __restrict__ WtDes, f16* __restrict__ WtIn, f16* __restrict__ WtR,
    f16* __restrict__ WtO1,
    int N, int nbf, int nbz)
{
  int b = blockIdx.x;
  int tid = threadIdx.x;
  if (b < nbf) {
    int w = (b * 256 + tid) >> 6;
    int lane = tid & 63;
    if (w < N) {
      const float* npr = num_prop + (size_t)w * 4;
      const float* cpr = cat_prop + (size_t)w * 3;
      float vn = b_num[lane];
#pragma unroll
      for (int k = 0; k < 4; k++) vn += npr[k] * W_num[k * 64 + lane];
      float vc = b_cat[lane];
#pragma unroll
      for (int k = 0; k < 3; k++) vc += cpr[k] * W_cat[k * 64 + lane];
      vn = LRELU(vn);
      vc = LRELU(vc);
      x0[(size_t)w * 192 + 64 + lane] = (f16)vn;
      x0[(size_t)w * 192 + 128 + lane] = (f16)vc;
    }
    return;
  }
  b -= nbf;
  if (b < nbz) {
    int i = b * 256 + tid;
    if (i < N) cursor[i] = 0;
    return;
  }
  b -= nbz;
  if (b < 192) {
    int idx = b * 256 + tid;
    if (idx < 64 * 768) { int n = idx / 768, k = idx % 768; WtDes[idx] = (f16)W_des[k * 64 + n]; }
    return;
  }
  b -= 192;
  if (b < 144) {
    int idx = b * 256 + tid;
    if (idx < 192 * 192) { int n = idx / 192, k = idx % 192; WtIn[idx] = (f16)W_in[k * 192 + n]; }
    return;
  }
  b -= 144;
  if (b < 432) {
    // WtR with K-interleaved layout: [root(192) | p0:rel0(64) rel1(64) | p1:... | p2:...]
    int idx = b * 256 + tid;
    if (idx < 192 * 576) {
      int n = idx / 576, k = idx % 576;
      float v;
      if (k < 192) {
        v = W_root[k * 192 + n];
      } else {
        int q = k - 192;
        int p = q >> 7, r = q & 127;
        int rel = (r >= 64) ? 1 : 0;
        int kk = p * 64 + (r & 63);
        v = W_rel[rel * 192 * 192 + kk * 192 + n];
      }
      WtR[idx] = (f16)v;
    }
    return;
  }
  b -= 432;
  {
    int idx = b * 256 + tid;
    if (idx < 192 * 192) { int n = idx / 192, k = idx % 192; WtO1[idx] = (f16)W_o1[k * 192 + n]; }
  }
}

// ---------------- bucket fill (1 atomic + 1 store per edge) ----------------
__global__ __launch_bounds__(256) void count_fill(
    const int* __restrict__ ei, const int* __restrict__ et,
    int* __restrict__ cursor, int* __restrict__ bucket, int E)
{
  int e = blockIdx.x * 256 + threadIdx.x;
  if (e >= E) return;
  int src = ei[e];
  int dst = ei[E + e];
  int r = et[e];
  int pos = atomicAdd(&cursor[dst], 1);
  if (pos < BCAP) bucket[(size_t)dst * BCAP + pos] = src | (r << 31);
}

// ---------------- des GEMM: [M,768]f32 @ Wt[64][768] -> x0 cols 0..63 ----------------
__global__ __launch_bounds__(256) void gemm_des_kernel(
    const float* __restrict__ A, const f16* __restrict__ Bt,
    const float* __restrict__ bias, f16* __restrict__ C, int M)
{
  __shared__ f16 lA[128 * 64];
  __shared__ f16 lB[64 * 64];
  const int tid = threadIdx.x, lane = tid & 63, wid = tid >> 6;
  const int wm = wid >> 1, wn = wid & 1;
  const int m0 = blockIdx.x * 128;
  f32x4 acc[4][2] = {};
  const int arow = tid >> 1, ahalf = tid & 1;
  int agr = m0 + arow;
  if (agr >= M) agr = M - 1;
  const float* asrc = A + (size_t)agr * 768 + ahalf * 32;
  for (int k0 = 0; k0 < 768; k0 += 64) {
    {
      const float4* s4 = reinterpret_cast<const float4*>(asrc + k0);
#pragma unroll
      for (int i = 0; i < 4; i++) {
        float4 u = s4[2 * i], w = s4[2 * i + 1];
        f16x8 h;
        h[0] = (f16)u.x; h[1] = (f16)u.y; h[2] = (f16)u.z; h[3] = (f16)u.w;
        h[4] = (f16)w.x; h[5] = (f16)w.y; h[6] = (f16)w.z; h[7] = (f16)w.w;
        int boff = arow * 128 + ahalf * 64 + i * 16;
        *reinterpret_cast<f16x8*>((char*)lA + swz(boff)) = h;
      }
    }
    {
#pragma unroll
      for (int i = 0; i < 2; i++) {
        int c = tid + i * 256;
        int n = c >> 3, k8 = c & 7;
        f16x8 h = *reinterpret_cast<const f16x8*>(Bt + (size_t)n * 768 + k0 + k8 * 8);
        *reinterpret_cast<f16x8*>((char*)lB + swz(n * 128 + k8 * 16)) = h;
      }
    }
    __syncthreads();
#pragma unroll
    for (int ks = 0; ks < 2; ks++) {
      f16x8 af[4], bf[2];
#pragma unroll
      for (int fm = 0; fm < 4; fm++) {
        int row = wm * 64 + fm * 16 + (lane & 15);
        af[fm] = *reinterpret_cast<const f16x8*>((const char*)lA + swz(row * 128 + ks * 64 + (lane >> 4) * 16));
      }
#pragma unroll
      for (int fn = 0; fn < 2; fn++) {
        int nn = wn * 32 + fn * 16 + (lane & 15);
        bf[fn] = *reinterpret_cast<const f16x8*>((const char*)lB + swz(nn * 128 + ks * 64 + (lane >> 4) * 16));
      }
#pragma unroll
      for (int fm = 0; fm < 4; fm++)
#pragma unroll
        for (int fn = 0; fn < 2; fn++)
          acc[fm][fn] = __builtin_amdgcn_mfma_f32_16x16x32_f16(af[fm], bf[fn], acc[fm][fn], 0, 0, 0);
    }
    __syncthreads();
  }
#pragma unroll
  for (int fm = 0; fm < 4; fm++) {
#pragma unroll
    for (int fn = 0; fn < 2; fn++) {
      int gc = wn * 32 + fn * 16 + (lane & 15);
      float b = bias[gc];
#pragma unroll
      for (int r = 0; r < 4; r++) {
        int gr = m0 + wm * 64 + fm * 16 + (lane >> 4) * 4 + r;
        if (gr < M) {
          float v = acc[fm][fn][r] + b;
          C[(size_t)gr * 192 + gc] = (f16)LRELU(v);
        }
      }
    }
  }
}

// ---------------- generic x-GEMM (NSEG=1 uses): [M,192] @ Wt[192][192] ----------------
template <int NSEG, bool RELU, bool OUT2>
__global__ __launch_bounds__(512) void gemm_x_kernel(
    const f16* __restrict__ A0, const f16* __restrict__ A1, const f16* __restrict__ A2,
    const f16* __restrict__ Bt, const float* __restrict__ bias,
    f16* __restrict__ C, int M,
    const float* __restrict__ W_o2, const float* __restrict__ b_o2,
    float* __restrict__ out)
{
  __shared__ f16 lA[128 * 64];
  __shared__ f16 lB[192 * 64];
  const int tid = threadIdx.x, lane = tid & 63, wid = tid >> 6;
  const int wm = wid >> 2, wn = wid & 3;
  const int m0 = blockIdx.x * 128;
  const int Ktot = NSEG * 192;
  f32x4 acc[4][3] = {};
  const f16* segs[3] = {A0, A1, A2};
  const int arow = tid >> 2, aq = tid & 3;
  int agr = m0 + arow;
  if (agr >= M) agr = M - 1;
  int seg = 0, kin = 0;
  for (int it = 0; it < NSEG * 3; it++) {
    {
      const f16x8* s8 = reinterpret_cast<const f16x8*>(segs[seg] + (size_t)agr * 192 + kin + aq * 16);
      f16x8 h0 = s8[0], h1 = s8[1];
      int b0 = arow * 128 + aq * 32;
      *reinterpret_cast<f16x8*>((char*)lA + swz(b0)) = h0;
      *reinterpret_cast<f16x8*>((char*)lA + swz(b0 + 16)) = h1;
    }
    {
      int kb = it * 64;
#pragma unroll
      for (int i = 0; i < 3; i++) {
        int c = tid + i * 512;
        int n = c >> 3, k8 = c & 7;
        f16x8 h = *reinterpret_cast<const f16x8*>(Bt + (size_t)n * Ktot + kb + k8 * 8);
        *reinterpret_cast<f16x8*>((char*)lB + swz(n * 128 + k8 * 16)) = h;
      }
    }
    __syncthreads();
#pragma unroll
    for (int ks = 0; ks < 2; ks++) {
      f16x8 af[4], bf[3];
#pragma unroll
      for (int fm = 0; fm < 4; fm++) {
        int row = wm * 64 + fm * 16 + (lane & 15);
        af[fm] = *reinterpret_cast<const f16x8*>((const char*)lA + swz(row * 128 + ks * 64 + (lane >> 4) * 16));
      }
#pragma unroll
      for (int fn = 0; fn < 3; fn++) {
        int nn = wn * 48 + fn * 16 + (lane & 15);
        bf[fn] = *reinterpret_cast<const f16x8*>((const char*)lB + swz(nn * 128 + ks * 64 + (lane >> 4) * 16));
      }
#pragma unroll
      for (int fm = 0; fm < 4; fm++)
#pragma unroll
        for (int fn = 0; fn < 3; fn++)
          acc[fm][fn] = __builtin_amdgcn_mfma_f32_16x16x32_f16(af[fm], bf[fn], acc[fm][fn], 0, 0, 0);
    }
    __syncthreads();
    kin += 64;
    if (kin == 192) { kin = 0; if (seg < NSEG - 1) seg++; }
  }
  if (OUT2) {
    __shared__ float red[128][2];
    for (int i = tid; i < 256; i += 512) ((float*)red)[i] = 0.f;
    __syncthreads();
    float bb[3], w2v[3][2];
#pragma unroll
    for (int fn = 0; fn < 3; fn++) {
      int gc = wn * 48 + fn * 16 + (lane & 15);
      bb[fn] = bias[gc];
      w2v[fn][0] = W_o2[gc * 2 + 0];
      w2v[fn][1] = W_o2[gc * 2 + 1];
    }
#pragma unroll
    for (int fm = 0; fm < 4; fm++) {
#pragma unroll
      for (int r = 0; r < 4; r++) {
        float p0 = 0.f, p1 = 0.f;
#pragma unroll
        for (int fn = 0; fn < 3; fn++) {
          float v = acc[fm][fn][r] + bb[fn];
          v = LRELU(v);
          p0 += v * w2v[fn][0];
          p1 += v * w2v[fn][1];
        }
#pragma unroll
        for (int m = 1; m < 16; m <<= 1) { p0 += __shfl_xor(p0, m); p1 += __shfl_xor(p1, m); }
        if ((lane & 15) == 0) {
          int lr = wm * 64 + fm * 16 + (lane >> 4) * 4 + r;
          atomicAdd(&red[lr][0], p0);
          atomicAdd(&red[lr][1], p1);
        }
      }
    }
    __syncthreads();
    if (tid < 256) {
      int gr = m0 + (tid >> 1);
      if (gr < M) out[(size_t)gr * 2 + (tid & 1)] = red[tid >> 1][tid & 1] + b_o2[tid & 1];
    }
  } else {
#pragma unroll
    for (int fm = 0; fm < 4; fm++) {
#pragma unroll
      for (int fn = 0; fn < 3; fn++) {
        int gc = wn * 48 + fn * 16 + (lane & 15);
        float b = bias[fn * 0 + gc];
#pragma unroll
        for (int r = 0; r < 4; r++) {
          int gr = m0 + wm * 64 + fm * 16 + (lane >> 4) * 4 + r;
          if (gr < M) {
            float v = acc[fm][fn][r] + b;
            if (RELU) v = LRELU(v);
            C[(size_t)gr * 192 + gc] = (f16)v;
          }
        }
      }
    }
  }
}

// ---------------- fused RGCN layer: out = [x | mean_r0 | mean_r1] @ WtR' + b ----------------
// K-chunks 0-2: x (root). Chunk-pairs p=0..2: gather 64-col slice of both relation means
// into LDS (reusing lA region), then 2 MFMA K-steps against interleaved WtR.
__global__ __launch_bounds__(512) void rgcn_fused_kernel(
    const f16* __restrict__ X, const int* __restrict__ bucket,
    const int* __restrict__ cursor, const f16* __restrict__ Bt,
    const float* __restrict__ bias, f16* __restrict__ C, int M)
{
  __shared__ char smem[32768 + 24576];   // [agg pair 32K | lB 24K]; lA aliases first 16K
  f16* lA = (f16*)smem;
  f16* lB = (f16*)(smem + 32768);
  const int tid = threadIdx.x, lane = tid & 63, wid = tid >> 6;
  const int wm = wid >> 2, wn = wid & 3;
  const int m0 = blockIdx.x * 128;
  f32x4 acc[4][3] = {};
  const int arow = tid >> 2, aq = tid & 3;
  int agr = m0 + arow;
  if (agr >= M) agr = M - 1;
  const int g = lane >> 4, sub = lane & 15;

  auto stage_lB = [&](int it) {
#pragma unroll
    for (int i = 0; i < 3; i++) {
      int c = tid + i * 512;
      int n = c >> 3, k8 = c & 7;
      f16x8 h = *reinterpret_cast<const f16x8*>(Bt + (size_t)n * 576 + it * 64 + k8 * 8);
      *reinterpret_cast<f16x8*>((char*)lB + swz(n * 128 + k8 * 16)) = h;
    }
  };
  auto mfma_step = [&](const char* abase) {
#pragma unroll
    for (int ks = 0; ks < 2; ks++) {
      f16x8 af[4], bf[3];
#pragma unroll
      for (int fm = 0; fm < 4; fm++) {
        int row = wm * 64 + fm * 16 + (lane & 15);
        af[fm] = *reinterpret_cast<const f16x8*>(abase + swz(row * 128 + ks * 64 + (lane >> 4) * 16));
      }
#pragma unroll
      for (int fn = 0; fn < 3; fn++) {
        int nn = wn * 48 + fn * 16 + (lane & 15);
        bf[fn] = *reinterpret_cast<const f16x8*>((const char*)lB + swz(nn * 128 + ks * 64 + (lane >> 4) * 16));
      }
#pragma unroll
      for (int fm = 0; fm < 4; fm++)
#pragma unroll
        for (int fn = 0; fn < 3; fn++)
          acc[fm][fn] = __builtin_amdgcn_mfma_f32_16x16x32_f16(af[fm], bf[fn], acc[fm][fn], 0, 0, 0);
    }
  };

  // ---- x chunks ----
  for (int it = 0; it < 3; ++it) {
    {
      const f16x8* s8 = reinterpret_cast<const f16x8*>(X + (size_t)agr * 192 + it * 64 + aq * 16);
      f16x8 h0 = s8[0], h1 = s8[1];
      int b0 = arow * 128 + aq * 32;
      *reinterpret_cast<f16x8*>((char*)lA + swz(b0)) = h0;
      *reinterpret_cast<f16x8*>((char*)lA + swz(b0 + 16)) = h1;
    }
    stage_lB(it);
    __syncthreads();
    mfma_step((const char*)lA);
    __syncthreads();
  }

  // ---- agg chunk-pairs ----
  for (int p = 0; p < 3; ++p) {
    // gather both relation means' 64-col slice for all 128 local rows
    for (int pass = 0; pass < 16; ++pass) {
      int dl = (pass << 3) + wid;
      int d = m0 + dl;
      int deg = 0;
      if (d < M) { deg = cursor[d]; if (deg > BCAP) deg = BCAP; }
      const int4* bk4 = reinterpret_cast<const int4*>(bucket + (size_t)d * BCAP);
      float a0[4] = {}, a1[4] = {};
      float c1f = 0.f;
      int nj = (deg + 15) >> 4;
      for (int j = 0; j < nj; ++j) {
        int4 ee = bk4[j * 4 + g];
#pragma unroll
        for (int i = 0; i < 4; ++i) {
          int idx = j * 16 + g * 4 + i;
          if (idx < deg) {
            int e = (i == 0) ? ee.x : (i == 1) ? ee.y : (i == 2) ? ee.z : ee.w;
            int src = e & 0x7fffffff;
            f16x4 v = *reinterpret_cast<const f16x4*>(X + (size_t)src * 192 + p * 64 + sub * 4);
            if (e < 0) {
              c1f += 1.f;
#pragma unroll
              for (int c = 0; c < 4; ++c) a1[c] += (float)v[c];
            } else {
#pragma unroll
              for (int c = 0; c < 4; ++c) a0[c] += (float)v[c];
            }
          }
        }
      }
#pragma unroll
      for (int c = 0; c < 4; ++c) {
        a0[c] += __shfl_xor(a0[c], 16); a0[c] += __shfl_xor(a0[c], 32);
        a1[c] += __shfl_xor(a1[c], 16); a1[c] += __shfl_xor(a1[c], 32);
      }
      c1f += __shfl_xor(c1f, 16); c1f += __shfl_xor(c1f, 32);
      if (g == 0) {
        float c0f = (float)deg - c1f;
        float i0 = 1.f / fmaxf(c0f, 1.f);
        float i1 = 1.f / fmaxf(c1f, 1.f);
        f16x4 o0, o1;
#pragma unroll
        for (int c = 0; c < 4; ++c) {
          o0[c] = (f16)(a0[c] * i0);
          o1[c] = (f16)(a1[c] * i1);
        }
        int boff = dl * 128 + sub * 8;
        *reinterpret_cast<f16x4*>((char*)lA + swz(boff)) = o0;
        *reinterpret_cast<f16x4*>((char*)lA + 16384 + swz(boff)) = o1;
      }
    }
#pragma unroll
    for (int s = 0; s < 2; ++s) {
      stage_lB(3 + p * 2 + s);
      __syncthreads();
      mfma_step((const char*)lA + s * 16384);
      __syncthreads();
    }
  }

  // ---- epilogue ----
#pragma unroll
  for (int fm = 0; fm < 4; fm++) {
#pragma unroll
    for (int fn = 0; fn < 3; fn++) {
      int gc = wn * 48 + fn * 16 + (lane & 15);
      float b = bias[gc];
#pragma unroll
      for (int r = 0; r < 4; r++) {
        int gr = m0 + wm * 64 + fm * 16 + (lane >> 4) * 4 + r;
        if (gr < M) {
          float v = acc[fm][fn][r] + b;
          C[(size_t)gr * 192 + gc] = (f16)v;
        }
      }
    }
  }
}

extern "C" void kernel_launch(void* const* d_in, const int* in_sizes, int n_in,
                              void* d_out, int out_size, void* d_ws, size_t ws_size,
                              hipStream_t stream)
{
  const float* des      = (const float*)d_in[0];
  const float* num_prop = (const float*)d_in[2];
  const float* cat_prop = (const float*)d_in[3];
  const int* edge_index = (const int*)d_in[4];
  const int* edge_type  = (const int*)d_in[5];
  const float* W_des = (const float*)d_in[6];
  const float* b_des = (const float*)d_in[7];
  const float* W_num = (const float*)d_in[8];
  const float* b_num = (const float*)d_in[9];
  const float* W_cat = (const float*)d_in[10];
  const float* b_cat = (const float*)d_in[11];
  const float* W_in  = (const float*)d_in[12];
  const float* b_in  = (const float*)d_in[13];
  const float* W_root= (const float*)d_in[14];
  const float* W_rel = (const float*)d_in[15];
  const float* b_rgcn= (const float*)d_in[16];
  const float* W_o1  = (const float*)d_in[17];
  const float* b_o1  = (const float*)d_in[18];
  const float* W_o2  = (const float*)d_in[19];
  const float* b_o2  = (const float*)d_in[20];
  float* out = (float*)d_out;

  const int N = in_sizes[2] / 4;
  const int E = in_sizes[5];
  (void)n_in; (void)out_size; (void)ws_size;

  char* base = (char*)d_ws;
  size_t off = 0;
  auto take = [&](size_t bytes) -> void* {
    void* p = base + off;
    off += (bytes + 255) & ~(size_t)255;
    return p;
  };
  f16* xA     = (f16*)take((size_t)N * 192 * 2);
  f16* xB     = (f16*)take((size_t)N * 192 * 2);
  int* bucket = (int*)take((size_t)N * BCAP * 4);
  int* cursor = (int*)take((size_t)N * 4);
  f16* WtDes  = (f16*)take(64 * 768 * 2);
  f16* WtIn   = (f16*)take(192 * 192 * 2);
  f16* WtR    = (f16*)take(192 * 576 * 2);
  f16* WtO1   = (f16*)take(192 * 192 * 2);

  const int nbf = (N + 3) / 4;
  const int nbz = (N + 255) / 256;
  const int nsetup = nbf + nbz + 192 + 144 + 432 + 144;
  setup_kernel<<<nsetup, 256, 0, stream>>>(
      num_prop, cat_prop, W_num, b_num, W_cat, b_cat,
      W_des, W_in, W_root, W_rel, W_o1,
      xA, cursor, WtDes, WtIn, WtR, WtO1, N, nbf, nbz);
  count_fill<<<(E + 255) / 256, 256, 0, stream>>>(edge_index, edge_type, cursor, bucket, E);
  gemm_des_kernel<<<(N + 127) / 128, 256, 0, stream>>>(des, WtDes, b_des, xA, N);
  // x1 = LReLU(x0 @ W_in + b_in)
  gemm_x_kernel<1, true, false><<<(N + 127) / 128, 512, 0, stream>>>(
      xA, xA, xA, WtIn, b_in, xB, N, nullptr, nullptr, nullptr);
  // rgcn 1 (fused gather + GEMM)
  rgcn_fused_kernel<<<(N + 127) / 128, 512, 0, stream>>>(
      xB, bucket, cursor, WtR, b_rgcn, xA, N);
  // rgcn 2
  rgcn_fused_kernel<<<(N + 127) / 128, 512, 0, stream>>>(
      xA, bucket, cursor, WtR, b_rgcn, xB, N);
  // out = LReLU(x @ W_o1 + b_o1) @ W_o2 + b_o2  (fused)
  gemm_x_kernel<1, false, true><<<(N + 127) / 128, 512, 0, stream>>>(
      xB, xB, xB, WtO1, b_o1, nullptr, N, W_o2, b_o2, out);
}

// Round 7
// 487.848 us; speedup vs baseline: 3.0732x; 3.0732x over previous
//
#include <hip/hip_runtime.h>

typedef _Float16 f16;
typedef _Float16 f16x4 __attribute__((ext_vector_type(4)));
typedef _Float16 f16x8 __attribute__((ext_vector_type(8)));
typedef float f32x4 __attribute__((ext_vector_type(4)));

#define LRELU(v) ((v) >= 0.f ? (v) : 0.01f * (v))

__device__ __forceinline__ int swz(int a) { return a ^ (((a >> 7) & 7) << 4); }

__device__ __forceinline__ f16x4 shflx4(f16x4 v, int m) {
  union { f16x4 h; int i[2]; } u;
  u.h = v;
  u.i[0] = __shfl_xor(u.i[0], m);
  u.i[1] = __shfl_xor(u.i[1], m);
  return u.h;
}

#define BCAP 64

// ---------------- fused setup: feat_small + zero_cursor + weight prep ----------------
__global__ __launch_bounds__(256) void setup_kernel(
    const float* __restrict__ num_prop, const float* __restrict__ cat_prop,
    const float* __restrict__ W_num, const float* __restrict__ b_num,
    const float* __restrict__ W_cat, const float* __restrict__ b_cat,
    const float* __restrict__ W_des, const float* __restrict__ W_in,
    const float* __restrict__ W_root, const float* __restrict__ W_rel,
    const float* __restrict__ W_o1,
    f16* __restrict__ x0, int* __restrict__ cursor,
    f16* __restrict__ WtDes, f16* __restrict__ WtIn, f16* __restrict__ WtR,
    f16* __restrict__ WtO1,
    int N, int nbf, int nbz)
{
  int b = blockIdx.x;
  int tid = threadIdx.x;
  if (b < nbf) {
    int w = (b * 256 + tid) >> 6;
    int lane = tid & 63;
    if (w < N) {
      const float* npr = num_prop + (size_t)w * 4;
      const float* cpr = cat_prop + (size_t)w * 3;
      float vn = b_num[lane];
#pragma unroll
      for (int k = 0; k < 4; k++) vn += npr[k] * W_num[k * 64 + lane];
      float vc = b_cat[lane];
#pragma unroll
      for (int k = 0; k < 3; k++) vc += cpr[k] * W_cat[k * 64 + lane];
      vn = LRELU(vn);
      vc = LRELU(vc);
      x0[(size_t)w * 192 + 64 + lane] = (f16)vn;
      x0[(size_t)w * 192 + 128 + lane] = (f16)vc;
    }
    return;
  }
  b -= nbf;
  if (b < nbz) {
    int i = b * 256 + tid;
    if (i < N) cursor[i] = 0;
    return;
  }
  b -= nbz;
  if (b < 192) {
    int idx = b * 256 + tid;
    if (idx < 64 * 768) { int n = idx / 768, k = idx % 768; WtDes[idx] = (f16)W_des[k * 64 + n]; }
    return;
  }
  b -= 192;
  if (b < 144) {
    int idx = b * 256 + tid;
    if (idx < 192 * 192) { int n = idx / 192, k = idx % 192; WtIn[idx] = (f16)W_in[k * 192 + n]; }
    return;
  }
  b -= 144;
  if (b < 432) {
    // WtR seg-major: [root(192) | rel0(192) | rel1(192)] per output column
    int idx = b * 256 + tid;
    if (idx < 192 * 576) {
      int n = idx / 576, k = idx % 576;
      int seg = k / 192, kk = k % 192;
      float v = (seg == 0) ? W_root[kk * 192 + n] : W_rel[(seg - 1) * 192 * 192 + kk * 192 + n];
      WtR[idx] = (f16)v;
    }
    return;
  }
  b -= 432;
  {
    int idx = b * 256 + tid;
    if (idx < 192 * 192) { int n = idx / 192, k = idx % 192; WtO1[idx] = (f16)W_o1[k * 192 + n]; }
  }
}

// ---------------- merged count_fill + des-GEMM (block-specialized, both 256 thr) ----------------
// blocks [0, nbDES): des GEMM tile; blocks [nbDES, ...): count_fill chunk.
__global__ __launch_bounds__(256) void cfdes_kernel(
    const float* __restrict__ A, const f16* __restrict__ Bt,
    const float* __restrict__ bias, f16* __restrict__ C, int M,
    const int* __restrict__ ei, const int* __restrict__ et,
    int* __restrict__ cursor, int* __restrict__ bucket, int E, int nbDES)
{
  __shared__ f16 lA[128 * 64];
  __shared__ f16 lB[64 * 64];
  if ((int)blockIdx.x >= nbDES) {
    int e = ((int)blockIdx.x - nbDES) * 256 + threadIdx.x;
    if (e < E) {
      int src = ei[e];
      int dst = ei[E + e];
      int r = et[e];
      int pos = atomicAdd(&cursor[dst], 1);
      if (pos < BCAP) bucket[(size_t)dst * BCAP + pos] = src | (r << 31);
    }
    return;
  }
  const int tid = threadIdx.x, lane = tid & 63, wid = tid >> 6;
  const int wm = wid >> 1, wn = wid & 1;
  const int m0 = blockIdx.x * 128;
  f32x4 acc[4][2] = {};
  const int arow = tid >> 1, ahalf = tid & 1;
  int agr = m0 + arow;
  if (agr >= M) agr = M - 1;
  const float* asrc = A + (size_t)agr * 768 + ahalf * 32;
  for (int k0 = 0; k0 < 768; k0 += 64) {
    {
      const float4* s4 = reinterpret_cast<const float4*>(asrc + k0);
#pragma unroll
      for (int i = 0; i < 4; i++) {
        float4 u = s4[2 * i], w = s4[2 * i + 1];
        f16x8 h;
        h[0] = (f16)u.x; h[1] = (f16)u.y; h[2] = (f16)u.z; h[3] = (f16)u.w;
        h[4] = (f16)w.x; h[5] = (f16)w.y; h[6] = (f16)w.z; h[7] = (f16)w.w;
        int boff = arow * 128 + ahalf * 64 + i * 16;
        *reinterpret_cast<f16x8*>((char*)lA + swz(boff)) = h;
      }
    }
    {
#pragma unroll
      for (int i = 0; i < 2; i++) {
        int c = tid + i * 256;
        int n = c >> 3, k8 = c & 7;
        f16x8 h = *reinterpret_cast<const f16x8*>(Bt + (size_t)n * 768 + k0 + k8 * 8);
        *reinterpret_cast<f16x8*>((char*)lB + swz(n * 128 + k8 * 16)) = h;
      }
    }
    __syncthreads();
#pragma unroll
    for (int ks = 0; ks < 2; ks++) {
      f16x8 af[4], bf[2];
#pragma unroll
      for (int fm = 0; fm < 4; fm++) {
        int row = wm * 64 + fm * 16 + (lane & 15);
        af[fm] = *reinterpret_cast<const f16x8*>((const char*)lA + swz(row * 128 + ks * 64 + (lane >> 4) * 16));
      }
#pragma unroll
      for (int fn = 0; fn < 2; fn++) {
        int nn = wn * 32 + fn * 16 + (lane & 15);
        bf[fn] = *reinterpret_cast<const f16x8*>((const char*)lB + swz(nn * 128 + ks * 64 + (lane >> 4) * 16));
      }
#pragma unroll
      for (int fm = 0; fm < 4; fm++)
#pragma unroll
        for (int fn = 0; fn < 2; fn++)
          acc[fm][fn] = __builtin_amdgcn_mfma_f32_16x16x32_f16(af[fm], bf[fn], acc[fm][fn], 0, 0, 0);
    }
    __syncthreads();
  }
#pragma unroll
  for (int fm = 0; fm < 4; fm++) {
#pragma unroll
    for (int fn = 0; fn < 2; fn++) {
      int gc = wn * 32 + fn * 16 + (lane & 15);
      float b = bias[gc];
#pragma unroll
      for (int r = 0; r < 4; r++) {
        int gr = m0 + wm * 64 + fm * 16 + (lane >> 4) * 4 + r;
        if (gr < M) {
          float v = acc[fm][fn][r] + b;
          C[(size_t)gr * 192 + gc] = (f16)LRELU(v);
        }
      }
    }
  }
}

// ---------------- generic x-GEMM: up to 3 f16 segments [M,192] @ Wt[192][NSEG*192] ----------------
template <int NSEG, bool RELU, bool OUT2>
__global__ __launch_bounds__(512) void gemm_x_kernel(
    const f16* __restrict__ A0, const f16* __restrict__ A1, const f16* __restrict__ A2,
    const f16* __restrict__ Bt, const float* __restrict__ bias,
    f16* __restrict__ C, int M,
    const float* __restrict__ W_o2, const float* __restrict__ b_o2,
    float* __restrict__ out)
{
  __shared__ f16 lA[128 * 64];
  __shared__ f16 lB[192 * 64];
  const int tid = threadIdx.x, lane = tid & 63, wid = tid >> 6;
  const int wm = wid >> 2, wn = wid & 3;
  const int m0 = blockIdx.x * 128;
  const int Ktot = NSEG * 192;
  f32x4 acc[4][3] = {};
  const f16* segs[3] = {A0, A1, A2};
  const int arow = tid >> 2, aq = tid & 3;
  int agr = m0 + arow;
  if (agr >= M) agr = M - 1;
  int seg = 0, kin = 0;
  for (int it = 0; it < NSEG * 3; it++) {
    {
      const f16x8* s8 = reinterpret_cast<const f16x8*>(segs[seg] + (size_t)agr * 192 + kin + aq * 16);
      f16x8 h0 = s8[0], h1 = s8[1];
      int b0 = arow * 128 + aq * 32;
      *reinterpret_cast<f16x8*>((char*)lA + swz(b0)) = h0;
      *reinterpret_cast<f16x8*>((char*)lA + swz(b0 + 16)) = h1;
    }
    {
      int kb = it * 64;
#pragma unroll
      for (int i = 0; i < 3; i++) {
        int c = tid + i * 512;
        int n = c >> 3, k8 = c & 7;
        f16x8 h = *reinterpret_cast<const f16x8*>(Bt + (size_t)n * Ktot + kb + k8 * 8);
        *reinterpret_cast<f16x8*>((char*)lB + swz(n * 128 + k8 * 16)) = h;
      }
    }
    __syncthreads();
#pragma unroll
    for (int ks = 0; ks < 2; ks++) {
      f16x8 af[4], bf[3];
#pragma unroll
      for (int fm = 0; fm < 4; fm++) {
        int row = wm * 64 + fm * 16 + (lane & 15);
        af[fm] = *reinterpret_cast<const f16x8*>((const char*)lA + swz(row * 128 + ks * 64 + (lane >> 4) * 16));
      }
#pragma unroll
      for (int fn = 0; fn < 3; fn++) {
        int nn = wn * 48 + fn * 16 + (lane & 15);
        bf[fn] = *reinterpret_cast<const f16x8*>((const char*)lB + swz(nn * 128 + ks * 64 + (lane >> 4) * 16));
      }
#pragma unroll
      for (int fm = 0; fm < 4; fm++)
#pragma unroll
        for (int fn = 0; fn < 3; fn++)
          acc[fm][fn] = __builtin_amdgcn_mfma_f32_16x16x32_f16(af[fm], bf[fn], acc[fm][fn], 0, 0, 0);
    }
    __syncthreads();
    kin += 64;
    if (kin == 192) { kin = 0; if (seg < NSEG - 1) seg++; }
  }
  if (OUT2) {
    __shared__ float red[128][2];
    for (int i = tid; i < 256; i += 512) ((float*)red)[i] = 0.f;
    __syncthreads();
    float bb[3], w2v[3][2];
#pragma unroll
    for (int fn = 0; fn < 3; fn++) {
      int gc = wn * 48 + fn * 16 + (lane & 15);
      bb[fn] = bias[gc];
      w2v[fn][0] = W_o2[gc * 2 + 0];
      w2v[fn][1] = W_o2[gc * 2 + 1];
    }
#pragma unroll
    for (int fm = 0; fm < 4; fm++) {
#pragma unroll
      for (int r = 0; r < 4; r++) {
        float p0 = 0.f, p1 = 0.f;
#pragma unroll
        for (int fn = 0; fn < 3; fn++) {
          float v = acc[fm][fn][r] + bb[fn];
          v = LRELU(v);
          p0 += v * w2v[fn][0];
          p1 += v * w2v[fn][1];
        }
#pragma unroll
        for (int m = 1; m < 16; m <<= 1) { p0 += __shfl_xor(p0, m); p1 += __shfl_xor(p1, m); }
        if ((lane & 15) == 0) {
          int lr = wm * 64 + fm * 16 + (lane >> 4) * 4 + r;
          atomicAdd(&red[lr][0], p0);
          atomicAdd(&red[lr][1], p1);
        }
      }
    }
    __syncthreads();
    if (tid < 256) {
      int gr = m0 + (tid >> 1);
      if (gr < M) out[(size_t)gr * 2 + (tid & 1)] = red[tid >> 1][tid & 1] + b_o2[tid & 1];
    }
  } else {
#pragma unroll
    for (int fm = 0; fm < 4; fm++) {
#pragma unroll
      for (int fn = 0; fn < 3; fn++) {
        int gc = wn * 48 + fn * 16 + (lane & 15);
        float b = bias[gc];
#pragma unroll
        for (int r = 0; r < 4; r++) {
          int gr = m0 + wm * 64 + fm * 16 + (lane >> 4) * 4 + r;
          if (gr < M) {
            float v = acc[fm][fn][r] + b;
            if (RELU) v = LRELU(v);
            C[(size_t)gr * 192 + gc] = (f16)v;
          }
        }
      }
    }
  }
}

// ---------------- gather-based per-(dst,rel) mean aggregation v5 ----------------
// v4 structure (dynamic slot loop + coalesced 128B loads) with PACKED-F16 accumulation:
// per-edge work is 6 v_pk_add_f16 instead of 12 cvt + 12 f32 adds. Divide stays f32.
__global__ __launch_bounds__(256) void agg_kernel(
    const f16* __restrict__ x, const int* __restrict__ bucket,
    const int* __restrict__ cursor,
    f16* __restrict__ agg0, f16* __restrict__ agg1, int N)
{
  int w = (blockIdx.x << 2) + (threadIdx.x >> 6);
  if (w >= N) return;
  const int lane = threadIdx.x & 63;
  const int g = lane >> 4, sub = lane & 15;
  int deg = cursor[w];
  if (deg > BCAP) deg = BCAP;
  const int4* bk4 = reinterpret_cast<const int4*>(bucket + (size_t)w * BCAP);
  f16x4 a0[3] = {}, a1[3] = {};
  float c1f = 0.f;
  int nj = (deg + 15) >> 4;
  for (int j = 0; j < nj; ++j) {
    int4 ee = bk4[j * 4 + g];
#pragma unroll
    for (int i = 0; i < 4; ++i) {
      int idx = j * 16 + g * 4 + i;
      if (idx < deg) {
        int e = (i == 0) ? ee.x : (i == 1) ? ee.y : (i == 2) ? ee.z : ee.w;
        int src = e & 0x7fffffff;
        const f16* rowp = x + (size_t)src * 192 + sub * 4;
        f16x4 v0 = *reinterpret_cast<const f16x4*>(rowp);
        f16x4 v1 = *reinterpret_cast<const f16x4*>(rowp + 64);
        f16x4 v2 = *reinterpret_cast<const f16x4*>(rowp + 128);
        if (e < 0) {
          c1f += 1.f;
          a1[0] += v0; a1[1] += v1; a1[2] += v2;
        } else {
          a0[0] += v0; a0[1] += v1; a0[2] += v2;
        }
      }
    }
  }
#pragma unroll
  for (int c = 0; c < 3; ++c) {
    a0[c] += shflx4(a0[c], 16); a0[c] += shflx4(a0[c], 32);
    a1[c] += shflx4(a1[c], 16); a1[c] += shflx4(a1[c], 32);
  }
  c1f += __shfl_xor(c1f, 16); c1f += __shfl_xor(c1f, 32);
  if (g == 0) {
    float c0f = (float)deg - c1f;
    float i0 = 1.f / fmaxf(c0f, 1.f);
    float i1 = 1.f / fmaxf(c1f, 1.f);
#pragma unroll
    for (int c = 0; c < 3; ++c) {
      f16x4 o0, o1;
#pragma unroll
      for (int k = 0; k < 4; ++k) {
        o0[k] = (f16)((float)a0[c][k] * i0);
        o1[k] = (f16)((float)a1[c][k] * i1);
      }
      *reinterpret_cast<f16x4*>(agg0 + (size_t)w * 192 + c * 64 + sub * 4) = o0;
      *reinterpret_cast<f16x4*>(agg1 + (size_t)w * 192 + c * 64 + sub * 4) = o1;
    }
  }
}

extern "C" void kernel_launch(void* const* d_in, const int* in_sizes, int n_in,
                              void* d_out, int out_size, void* d_ws, size_t ws_size,
                              hipStream_t stream)
{
  const float* des      = (const float*)d_in[0];
  const float* num_prop = (const float*)d_in[2];
  const float* cat_prop = (const float*)d_in[3];
  const int* edge_index = (const int*)d_in[4];
  const int* edge_type  = (const int*)d_in[5];
  const float* W_des = (const float*)d_in[6];
  const float* b_des = (const float*)d_in[7];
  const float* W_num = (const float*)d_in[8];
  const float* b_num = (const float*)d_in[9];
  const float* W_cat = (const float*)d_in[10];
  const float* b_cat = (const float*)d_in[11];
  const float* W_in  = (const float*)d_in[12];
  const float* b_in  = (const float*)d_in[13];
  const float* W_root= (const float*)d_in[14];
  const float* W_rel = (const float*)d_in[15];
  const float* b_rgcn= (const float*)d_in[16];
  const float* W_o1  = (const float*)d_in[17];
  const float* b_o1  = (const float*)d_in[18];
  const float* W_o2  = (const float*)d_in[19];
  const float* b_o2  = (const float*)d_in[20];
  float* out = (float*)d_out;

  const int N = in_sizes[2] / 4;
  const int E = in_sizes[5];
  (void)n_in; (void)out_size; (void)ws_size;

  char* base = (char*)d_ws;
  size_t off = 0;
  auto take = [&](size_t bytes) -> void* {
    void* p = base + off;
    off += (bytes + 255) & ~(size_t)255;
    return p;
  };
  f16* xA     = (f16*)take((size_t)N * 192 * 2);
  f16* xB     = (f16*)take((size_t)N * 192 * 2);
  f16* agg0   = (f16*)take((size_t)N * 192 * 2);
  f16* agg1   = (f16*)take((size_t)N * 192 * 2);
  int* bucket = (int*)take((size_t)N * BCAP * 4);
  int* cursor = (int*)take((size_t)N * 4);
  f16* WtDes  = (f16*)take(64 * 768 * 2);
  f16* WtIn   = (f16*)take(192 * 192 * 2);
  f16* WtR    = (f16*)take(192 * 576 * 2);
  f16* WtO1   = (f16*)take(192 * 192 * 2);

  const int nbf = (N + 3) / 4;
  const int nbz = (N + 255) / 256;
  const int nsetup = nbf + nbz + 192 + 144 + 432 + 144;
  setup_kernel<<<nsetup, 256, 0, stream>>>(
      num_prop, cat_prop, W_num, b_num, W_cat, b_cat,
      W_des, W_in, W_root, W_rel, W_o1,
      xA, cursor, WtDes, WtIn, WtR, WtO1, N, nbf, nbz);
  // merged: des GEMM (blocks first) + count_fill (blocks behind)
  const int nbDES = (N + 127) / 128;
  const int nbCF = (E + 255) / 256;
  cfdes_kernel<<<nbDES + nbCF, 256, 0, stream>>>(
      des, WtDes, b_des, xA, N, edge_index, edge_type, cursor, bucket, E, nbDES);
  // x1 = LReLU(x0 @ W_in + b_in)
  gemm_x_kernel<1, true, false><<<(N + 127) / 128, 512, 0, stream>>>(
      xA, xA, xA, WtIn, b_in, xB, N, nullptr, nullptr, nullptr);
  // rgcn 1
  agg_kernel<<<(N + 3) / 4, 256, 0, stream>>>(xB, bucket, cursor, agg0, agg1, N);
  gemm_x_kernel<3, false, false><<<(N + 127) / 128, 512, 0, stream>>>(
      xB, agg0, agg1, WtR, b_rgcn, xA, N, nullptr, nullptr, nullptr);
  // rgcn 2
  agg_kernel<<<(N + 3) / 4, 256, 0, stream>>>(xA, bucket, cursor, agg0, agg1, N);
  gemm_x_kernel<3, false, false><<<(N + 127) / 128, 512, 0, stream>>>(
      xA, agg0, agg1, WtR, b_rgcn, xB, N, nullptr, nullptr, nullptr);
  // out = LReLU(x @ W_o1 + b_o1) @ W_o2 + b_o2  (fused)
  gemm_x_kernel<1, false, true><<<(N + 127) / 128, 512, 0, stream>>>(
      xB, xB, xB, WtO1, b_o1, nullptr, N, W_o2, b_o2, out);
}